// Round 2
// baseline (1074.052 us; speedup 1.0000x reference)
//
#include <hip/hip_runtime.h>
#include <math.h>

// Problem constants (B, S, E, WIN) = (8, 2048, 512, 11)
#define B_    8
#define S_    2048
#define E_    512
#define WIN_  11
#define WW    5              // WIN/2
#define FLATF (WIN_ * E_)    // 5632 floats per flat window
#define F4C   (FLATF / 4)    // 1408 float4 per W row
#define E4C   (E_ / 4)       // 128 float4 per x row

// One block per sequence position s. 512 threads = 8 waves.
// Waves 0-3 (half 0) handle b = 0..3, waves 4-7 (half 1) handle b = 4..7.
// Each half's 256 threads cover the f-axis (1408 float4) in 6 strided steps.
// W[s] is read twice per block (once per half) — second read hits L1/L2.
// Per-thread state: acc[4][11] = 44 regs + wv[11] float4 = 44 regs -> ~115 VGPR,
// giving 4 waves/SIMD (2 blocks/CU) for latency hiding of the HBM W-stream.
__global__ __launch_bounds__(512, 4)
void win_attn_kernel(const float* __restrict__ x,
                     const float* __restrict__ W,
                     const float* __restrict__ bias,
                     float* __restrict__ out)
{
    const int s    = blockIdx.x;
    const int tid  = threadIdx.x;
    const int wid  = tid >> 6;        // wave 0..7
    const int half = tid >> 8;        // 0: b 0-3, 1: b 4-7
    const int t    = tid & 255;       // index within half

    const float4* __restrict__ X4 = reinterpret_cast<const float4*>(x);
    const float4* __restrict__ W4 =
        reinterpret_cast<const float4*>(W) + (size_t)s * (size_t)(F4C * WIN_);

    float acc[4][WIN_];
    #pragma unroll
    for (int bb = 0; bb < 4; ++bb)
        #pragma unroll
        for (int w = 0; w < WIN_; ++w) acc[bb][w] = 0.f;

    // ---- Phase 1: streamed dot products over f ----
    for (int k = 0; k < 6; ++k) {
        const int f4 = t + (k << 8);
        if (f4 < F4C) {
            float4 wv[WIN_];
            #pragma unroll
            for (int w = 0; w < WIN_; ++w) wv[w] = W4[w * F4C + f4];

            const int wp  = f4 >> 7;      // window row (0..10)
            const int e4  = f4 & 127;     // float4 index within row
            const int row = s - WW + wp;
            const bool valid = (row >= 0) && (row < S_);

            #pragma unroll
            for (int bb = 0; bb < 4; ++bb) {
                const int b = (half << 2) + bb;
                float4 xv = make_float4(0.f, 0.f, 0.f, 0.f);
                if (valid) xv = X4[((size_t)b * S_ + row) * E4C + e4];
                #pragma unroll
                for (int w = 0; w < WIN_; ++w) {
                    acc[bb][w] = fmaf(xv.x, wv[w].x, acc[bb][w]);
                    acc[bb][w] = fmaf(xv.y, wv[w].y, acc[bb][w]);
                    acc[bb][w] = fmaf(xv.z, wv[w].z, acc[bb][w]);
                    acc[bb][w] = fmaf(xv.w, wv[w].w, acc[bb][w]);
                }
            }
        }
    }

    // ---- wave-level butterfly reduction ----
    #pragma unroll
    for (int bb = 0; bb < 4; ++bb)
        #pragma unroll
        for (int w = 0; w < WIN_; ++w) {
            float v = acc[bb][w];
            v += __shfl_xor(v, 32, 64);
            v += __shfl_xor(v, 16, 64);
            v += __shfl_xor(v,  8, 64);
            v += __shfl_xor(v,  4, 64);
            v += __shfl_xor(v,  2, 64);
            v += __shfl_xor(v,  1, 64);
            acc[bb][w] = v;
        }

    __shared__ float red[8][4 * WIN_];
    __shared__ float gates[B_ * WIN_];

    if ((tid & 63) == 0) {
        #pragma unroll
        for (int bb = 0; bb < 4; ++bb)
            #pragma unroll
            for (int w = 0; w < WIN_; ++w)
                red[wid][bb * WIN_ + w] = acc[bb][w];
    }
    __syncthreads();

    if (tid < B_ * WIN_) {
        const int b = tid / WIN_;
        const int w = tid % WIN_;
        const int h = b >> 2;
        const int i = (b & 3) * WIN_ + w;
        float v = red[h * 4 + 0][i] + red[h * 4 + 1][i]
                + red[h * 4 + 2][i] + red[h * 4 + 3][i];
        v += bias[s * WIN_ + w];
        gates[tid] = 1.f / (1.f + expf(-v));
    }
    __syncthreads();

    // ---- Phase 2: score + tanh (x rows L2/L3 hot) ----
    float4* __restrict__ OUT4 = reinterpret_cast<float4*>(out);
    #pragma unroll
    for (int it = 0; it < 2; ++it) {
        const int i  = tid + (it << 9);   // 0..1023 -> (b, e4)
        const int b  = i >> 7;
        const int e4 = i & 127;
        float4 sc = make_float4(0.f, 0.f, 0.f, 0.f);
        #pragma unroll
        for (int w = 0; w < WIN_; ++w) {
            const int row = s - WW + w;
            if (row >= 0 && row < S_) {
                const float g   = gates[b * WIN_ + w];
                const float4 xv = X4[((size_t)b * S_ + row) * E4C + e4];
                sc.x = fmaf(g, xv.x, sc.x);
                sc.y = fmaf(g, xv.y, sc.y);
                sc.z = fmaf(g, xv.z, sc.z);
                sc.w = fmaf(g, xv.w, sc.w);
            }
        }
        float4 o;
        o.x = tanhf(sc.x);
        o.y = tanhf(sc.y);
        o.z = tanhf(sc.z);
        o.w = tanhf(sc.w);
        OUT4[((size_t)b * S_ + s) * E4C + e4] = o;
    }
}

extern "C" void kernel_launch(void* const* d_in, const int* in_sizes, int n_in,
                              void* d_out, int out_size, void* d_ws, size_t ws_size,
                              hipStream_t stream)
{
    const float* x    = (const float*)d_in[0];
    const float* W    = (const float*)d_in[1];
    const float* bias = (const float*)d_in[2];
    float* out        = (float*)d_out;

    win_attn_kernel<<<dim3(S_), dim3(512), 0, stream>>>(x, W, bias, out);
}

// Round 3
// 230.037 us; speedup vs baseline: 4.6690x; 4.6690x over previous
//
#include <hip/hip_runtime.h>
#include <math.h>

// Problem constants (B, S, E, WIN) = (8, 2048, 512, 11)
#define B_    8
#define S_    2048
#define E_    512
#define WIN_  11
#define WW    5              // WIN/2
#define FLATF (WIN_ * E_)    // 5632 floats per flat window
#define F4C   (FLATF / 4)    // 1408 float4 per W row
#define E4C   (E_ / 4)       // 128 float4 per x row

// One block per sequence position s. 512 threads = 8 waves = 4 w-groups.
// w-group wg (128 threads, 2 waves) owns window rows w = wg*3 .. min(wg*3+2, 10).
// Each wg covers the full f-axis (1408 float4) in 11 strided steps of 128,
// so f4 = t + 128k  =>  window row index = k, e4 = t (index math vanishes).
// W[s] is read exactly once per block (wgs own disjoint rows); x rows are read
// by all 4 wgs (L1/L2/L3-resident, x = 33.5 MB total).
// Per-thread state: acc[8][3]=24 + xv[8]=32 + wv[3]=12 + addr -> ~100 VGPR
// (<=128 tier: 4 waves/SIMD, 2 blocks/CU) with NO forced launch bounds — the
// round-2 lesson: forcing occupancy causes scratch spills (WRITE_SIZE 2.1 GB).
__global__ __launch_bounds__(512)
void win_attn_kernel(const float* __restrict__ x,
                     const float* __restrict__ W,
                     const float* __restrict__ bias,
                     float* __restrict__ out)
{
    const int s    = blockIdx.x;
    const int tid  = threadIdx.x;   // 0..511
    const int wid  = tid >> 6;      // wave 0..7
    const int wg   = tid >> 7;      // w-group 0..3
    const int t    = tid & 127;     // f-slice index within w-group
    const int wbase = wg * 3;       // first window row owned by this wg

    const float4* __restrict__ X4 = reinterpret_cast<const float4*>(x);
    const float4* __restrict__ W4 =
        reinterpret_cast<const float4*>(W) + (size_t)s * (size_t)(F4C * WIN_);

    float acc[B_][3];
    #pragma unroll
    for (int b = 0; b < B_; ++b)
        #pragma unroll
        for (int j = 0; j < 3; ++j) acc[b][j] = 0.f;

    // ---- Phase 1: streamed dot products over f (W read exactly once) ----
    #pragma unroll 1
    for (int k = 0; k < WIN_; ++k) {
        const int f4  = t + (k << 7);       // window row == k, e4 == t
        const int row = s - WW + k;
        const bool valid = (row >= 0) && (row < S_);

        float4 wv[3];
        #pragma unroll
        for (int j = 0; j < 3; ++j)
            if (wbase + j < WIN_)           // wave-uniform guard (wg3 has 2 rows)
                wv[j] = W4[(wbase + j) * F4C + f4];

        #pragma unroll
        for (int b = 0; b < B_; ++b) {
            float4 xv = make_float4(0.f, 0.f, 0.f, 0.f);
            if (valid) xv = X4[((size_t)b * S_ + row) * E4C + t];
            #pragma unroll
            for (int j = 0; j < 3; ++j) {
                if (wbase + j < WIN_) {
                    acc[b][j] = fmaf(xv.x, wv[j].x, acc[b][j]);
                    acc[b][j] = fmaf(xv.y, wv[j].y, acc[b][j]);
                    acc[b][j] = fmaf(xv.z, wv[j].z, acc[b][j]);
                    acc[b][j] = fmaf(xv.w, wv[j].w, acc[b][j]);
                }
            }
        }
    }

    // ---- wave-level butterfly reduction (sum over 64 lanes) ----
    #pragma unroll
    for (int b = 0; b < B_; ++b)
        #pragma unroll
        for (int j = 0; j < 3; ++j) {
            float v = acc[b][j];
            v += __shfl_xor(v, 32, 64);
            v += __shfl_xor(v, 16, 64);
            v += __shfl_xor(v,  8, 64);
            v += __shfl_xor(v,  4, 64);
            v += __shfl_xor(v,  2, 64);
            v += __shfl_xor(v,  1, 64);
            acc[b][j] = v;
        }

    __shared__ float red[8][B_ * 3];     // per-wave partial sums
    __shared__ float gates[B_ * WIN_];

    if ((tid & 63) == 0) {
        #pragma unroll
        for (int b = 0; b < B_; ++b)
            #pragma unroll
            for (int j = 0; j < 3; ++j)
                red[wid][b * 3 + j] = acc[b][j];
    }
    __syncthreads();

    // combine the 2 waves of each wg, add bias, sigmoid
    if (tid < B_ * 12) {
        const int b   = tid / 12;
        const int jj  = tid % 12;
        const int g   = jj / 3;          // which w-group
        const int j   = jj % 3;
        const int w   = g * 3 + j;
        if (w < WIN_) {
            float v = red[g * 2 + 0][b * 3 + j] + red[g * 2 + 1][b * 3 + j];
            v += bias[s * WIN_ + w];
            gates[b * WIN_ + w] = 1.f / (1.f + expf(-v));
        }
    }
    __syncthreads();

    // ---- Phase 2: score + tanh (x rows L1/L2/L3 hot) ----
    float4* __restrict__ OUT4 = reinterpret_cast<float4*>(out);
    #pragma unroll
    for (int it = 0; it < 2; ++it) {
        const int i  = tid + (it << 9);   // 0..1023 -> (b, e4)
        const int b  = i >> 7;
        const int e4 = i & 127;
        float4 sc = make_float4(0.f, 0.f, 0.f, 0.f);
        #pragma unroll
        for (int w = 0; w < WIN_; ++w) {
            const int row = s - WW + w;
            if (row >= 0 && row < S_) {
                const float g   = gates[b * WIN_ + w];
                const float4 xv = X4[((size_t)b * S_ + row) * E4C + e4];
                sc.x = fmaf(g, xv.x, sc.x);
                sc.y = fmaf(g, xv.y, sc.y);
                sc.z = fmaf(g, xv.z, sc.z);
                sc.w = fmaf(g, xv.w, sc.w);
            }
        }
        float4 o;
        o.x = tanhf(sc.x);
        o.y = tanhf(sc.y);
        o.z = tanhf(sc.z);
        o.w = tanhf(sc.w);
        OUT4[((size_t)b * S_ + s) * E4C + e4] = o;
    }
}

extern "C" void kernel_launch(void* const* d_in, const int* in_sizes, int n_in,
                              void* d_out, int out_size, void* d_ws, size_t ws_size,
                              hipStream_t stream)
{
    const float* x    = (const float*)d_in[0];
    const float* W    = (const float*)d_in[1];
    const float* bias = (const float*)d_in[2];
    float* out        = (float*)d_out;

    win_attn_kernel<<<dim3(S_), dim3(512), 0, stream>>>(x, W, bias, out);
}

// Round 4
// 206.768 us; speedup vs baseline: 5.1945x; 1.1125x over previous
//
#include <hip/hip_runtime.h>
#include <math.h>

// Problem constants (B, S, E, WIN) = (8, 2048, 512, 11)
#define B_    8
#define S_    2048
#define E_    512
#define WIN_  11
#define WW    5              // WIN/2
#define F4C   1408           // float4 per W row (5632/4)
#define E4C   128            // float4 per x row (512/4)

// ---------------------------------------------------------------------------
// Kernel A: partial gate dot-products.
// Grid (11, 2048): block (wp, s) handles window-position wp of sequence s.
// It reads W[s, w, wp*512 : (wp+1)*512] for all 11 w (22.5 KB, each W byte
// read exactly once chip-wide) and x[b, s-5+wp, :] for all 8 b.
// 256 threads = 4 waves; wave bg covers batches {bg, bg+4}; lane covers
// e4 = {lane, lane+64}. Per-thread state: acc[2][11]=22 + xv[4]=16 + addr
// -> ~70 VGPR -> ~6 waves/SIMD. 22 independent W loads per thread (unrolled
// w-loop) -> deep memory-level parallelism; 22528 blocks -> full occupancy.
// Output: P[((s*8 + b)*11 + w)*11 + wp] partial sums (7.9 MB in d_ws).
// ---------------------------------------------------------------------------
__global__ __launch_bounds__(256)
void win_gate_partial(const float* __restrict__ x,
                      const float* __restrict__ W,
                      float* __restrict__ P)
{
    const int wp   = blockIdx.x;      // 0..10
    const int s    = blockIdx.y;      // 0..2047
    const int tid  = threadIdx.x;
    const int bg   = tid >> 6;        // wave id 0..3 -> b in {bg, bg+4}
    const int lane = tid & 63;

    const int row   = s - WW + wp;
    const bool valid = (row >= 0) && (row < S_);

    if (!valid) {
        // contribution is zero (PAD_VAL = 0): write zero partials, done.
        if (lane < WIN_)
            P[(((size_t)s * B_ + bg) * WIN_ + lane) * WIN_ + wp] = 0.f;
        if (lane >= 32 && lane < 32 + WIN_)
            P[(((size_t)s * B_ + bg + 4) * WIN_ + (lane - 32)) * WIN_ + wp] = 0.f;
        return;
    }

    const float4* __restrict__ X4 = reinterpret_cast<const float4*>(x);
    const float4* __restrict__ W4 = reinterpret_cast<const float4*>(W)
        + (size_t)s * (WIN_ * F4C) + (size_t)wp * E4C;

    // x fragments: 2 batches x 2 float4
    const float4 xa0 = X4[((size_t)bg       * S_ + row) * E4C + lane];
    const float4 xa1 = X4[((size_t)bg       * S_ + row) * E4C + lane + 64];
    const float4 xb0 = X4[((size_t)(bg + 4) * S_ + row) * E4C + lane];
    const float4 xb1 = X4[((size_t)(bg + 4) * S_ + row) * E4C + lane + 64];

    float accA[WIN_], accB[WIN_];
    #pragma unroll
    for (int w = 0; w < WIN_; ++w) {
        const float4 w0 = W4[(size_t)w * F4C + lane];
        const float4 w1 = W4[(size_t)w * F4C + lane + 64];
        float a = 0.f, b = 0.f;
        a = fmaf(xa0.x, w0.x, a); a = fmaf(xa0.y, w0.y, a);
        a = fmaf(xa0.z, w0.z, a); a = fmaf(xa0.w, w0.w, a);
        a = fmaf(xa1.x, w1.x, a); a = fmaf(xa1.y, w1.y, a);
        a = fmaf(xa1.z, w1.z, a); a = fmaf(xa1.w, w1.w, a);
        b = fmaf(xb0.x, w0.x, b); b = fmaf(xb0.y, w0.y, b);
        b = fmaf(xb0.z, w0.z, b); b = fmaf(xb0.w, w0.w, b);
        b = fmaf(xb1.x, w1.x, b); b = fmaf(xb1.y, w1.y, b);
        b = fmaf(xb1.z, w1.z, b); b = fmaf(xb1.w, w1.w, b);
        accA[w] = a; accB[w] = b;
    }

    // full-wave butterfly: every lane ends with the complete e-sum
    #pragma unroll
    for (int w = 0; w < WIN_; ++w) {
        float a = accA[w], b = accB[w];
        a += __shfl_xor(a, 32, 64);  b += __shfl_xor(b, 32, 64);
        a += __shfl_xor(a, 16, 64);  b += __shfl_xor(b, 16, 64);
        a += __shfl_xor(a,  8, 64);  b += __shfl_xor(b,  8, 64);
        a += __shfl_xor(a,  4, 64);  b += __shfl_xor(b,  4, 64);
        a += __shfl_xor(a,  2, 64);  b += __shfl_xor(b,  2, 64);
        a += __shfl_xor(a,  1, 64);  b += __shfl_xor(b,  1, 64);
        accA[w] = a; accB[w] = b;
    }

    // lanes 0..10 store b=bg, lanes 32..42 store b=bg+4 (static-index select)
    float va = 0.f, vb = 0.f;
    #pragma unroll
    for (int w = 0; w < WIN_; ++w) {
        if (lane == w)      va = accA[w];
        if (lane == 32 + w) vb = accB[w];
    }
    if (lane < WIN_)
        P[(((size_t)s * B_ + bg) * WIN_ + lane) * WIN_ + wp] = va;
    if (lane >= 32 && lane < 32 + WIN_)
        P[(((size_t)s * B_ + bg + 4) * WIN_ + (lane - 32)) * WIN_ + wp] = vb;
}

// ---------------------------------------------------------------------------
// Kernel B: combine partials -> sigmoid gates -> score + tanh.
// Grid (2048): block per s, 256 threads. x rows are L2/L3-hot.
// ---------------------------------------------------------------------------
__global__ __launch_bounds__(256)
void win_score(const float* __restrict__ x,
               const float* __restrict__ bias,
               const float* __restrict__ P,
               float* __restrict__ out)
{
    const int s   = blockIdx.x;
    const int tid = threadIdx.x;

    __shared__ float gates[B_ * WIN_];
    if (tid < B_ * WIN_) {
        const int b = tid / WIN_;
        const int w = tid % WIN_;
        const float* p = P + (((size_t)s * B_ + b) * WIN_ + w) * WIN_;
        float v = 0.f;
        #pragma unroll
        for (int wp = 0; wp < WIN_; ++wp) v += p[wp];
        v += bias[s * WIN_ + w];
        gates[tid] = 1.f / (1.f + expf(-v));
    }
    __syncthreads();

    const float4* __restrict__ X4   = reinterpret_cast<const float4*>(x);
    float4* __restrict__       OUT4 = reinterpret_cast<float4*>(out);

    #pragma unroll
    for (int it = 0; it < 4; ++it) {
        const int i  = tid + (it << 8);   // 0..1023 -> (b, e4)
        const int b  = i >> 7;
        const int e4 = i & 127;
        float4 sc = make_float4(0.f, 0.f, 0.f, 0.f);
        #pragma unroll
        for (int w = 0; w < WIN_; ++w) {
            const int row = s - WW + w;
            if (row >= 0 && row < S_) {
                const float g   = gates[b * WIN_ + w];
                const float4 xv = X4[((size_t)b * S_ + row) * E4C + e4];
                sc.x = fmaf(g, xv.x, sc.x);
                sc.y = fmaf(g, xv.y, sc.y);
                sc.z = fmaf(g, xv.z, sc.z);
                sc.w = fmaf(g, xv.w, sc.w);
            }
        }
        float4 o;
        o.x = tanhf(sc.x);
        o.y = tanhf(sc.y);
        o.z = tanhf(sc.z);
        o.w = tanhf(sc.w);
        OUT4[((size_t)b * S_ + s) * E4C + e4] = o;
    }
}

extern "C" void kernel_launch(void* const* d_in, const int* in_sizes, int n_in,
                              void* d_out, int out_size, void* d_ws, size_t ws_size,
                              hipStream_t stream)
{
    const float* x    = (const float*)d_in[0];
    const float* W    = (const float*)d_in[1];
    const float* bias = (const float*)d_in[2];
    float* out        = (float*)d_out;
    float* P          = (float*)d_ws;   // 2048*8*11*11 floats = 7.93 MB

    win_gate_partial<<<dim3(WIN_, S_), dim3(256), 0, stream>>>(x, W, P);
    win_score<<<dim3(S_), dim3(256), 0, stream>>>(x, bias, P, out);
}

// Round 5
// 181.515 us; speedup vs baseline: 5.9171x; 1.1391x over previous
//
#include <hip/hip_runtime.h>
#include <math.h>

// Problem constants (B, S, E, WIN) = (8, 2048, 512, 11)
#define B_    8
#define S_    2048
#define E_    512
#define WIN_  11
#define WW    5              // WIN/2
#define F4C   1408           // float4 per W row (5632/4)
#define E4C   128            // float4 per x row (512/4)
#define NBLKA (S_ * WIN_)    // 22528 blocks in kernel A
#define CPX_A (NBLKA / 8)    // 2816 blocks per XCD (exact)
#define PSTR  (B_ * WIN_)    // 88 partials per (s,wp) block

// ---------------------------------------------------------------------------
// Kernel A: partial gate dot-products, W staged via global_load_lds.
// Block sw = s*11+wp handles window-position wp of sequence s:
//   - stages W[s, w, wp*512:(wp+1)*512] for all 11 w (22.5 KB) into LDS with
//     global_load_lds width-16 (deep HW queue -> beats the plain-load
//     Little's-law BW wall; W read EXACTLY once per block from HBM)
//   - wave wid covers batches {wid, wid+4}, lanes cover e4 {lane, lane+64}
//   - butterfly-reduce, store 88 CONTIGUOUS floats at P + sw*88
// XCD swizzle: each XCD gets a contiguous (s,wp) range -> x rows L2-local.
// ---------------------------------------------------------------------------
__global__ __launch_bounds__(256)
void win_gate_partial(const float* __restrict__ x,
                      const float* __restrict__ W,
                      float* __restrict__ P)
{
    const int bid = blockIdx.x;
    const int sw  = (bid & 7) * CPX_A + (bid >> 3);   // bijective (22528 % 8 == 0)
    const int s   = sw / WIN_;
    const int wp  = sw - s * WIN_;

    const int tid  = threadIdx.x;
    const int wid  = tid >> 6;      // wave 0..3
    const int lane = tid & 63;

    float* __restrict__ Pblk = P + (size_t)sw * PSTR;

    const int row = s - WW + wp;
    if (row < 0 || row >= S_) {     // block-uniform early out: zero partials
        if (tid < PSTR) Pblk[tid] = 0.f;
        return;
    }

    const float4* __restrict__ X4 = reinterpret_cast<const float4*>(x);
    const float4* __restrict__ W4 = reinterpret_cast<const float4*>(W)
        + (size_t)s * (WIN_ * F4C) + (size_t)wp * E4C;

    __shared__ float4 Wlds[WIN_ * E4C];   // 1408 float4 = 22.5 KB

    // x fragments (VGPR loads, L2/L3-hot) issued before staging to overlap
    const float4 xa0 = X4[((size_t)wid       * S_ + row) * E4C + lane];
    const float4 xa1 = X4[((size_t)wid       * S_ + row) * E4C + lane + 64];
    const float4 xb0 = X4[((size_t)(wid + 4) * S_ + row) * E4C + lane];
    const float4 xb1 = X4[((size_t)(wid + 4) * S_ + row) * E4C + lane + 64];

    // stage the 11 x 128-float4 W pieces (stride F4C) into linear LDS.
    // global src is per-lane (gather); LDS dest = wave-uniform base + lane*16.
    #pragma unroll
    for (int j = 0; j < 6; ++j) {
        const int m = j * 256 + tid;          // float4 index in [0,1536)
        if (j < 5 || wid < 2) {               // wave-uniform guard (m < 1408)
            const int w  = m >> 7;
            const int e4 = m & 127;
            const float4* src = W4 + (size_t)w * F4C + e4;
            __builtin_amdgcn_global_load_lds(
                (const __attribute__((address_space(1))) void*)src,
                (__attribute__((address_space(3))) void*)&Wlds[m],
                16, 0, 0);
        }
    }
    __syncthreads();   // drains vmcnt (staging + x loads)

    float accA[WIN_], accB[WIN_];
    #pragma unroll
    for (int w = 0; w < WIN_; ++w) {
        const float4 w0 = Wlds[w * E4C + lane];        // ds_read_b128, conflict-free
        const float4 w1 = Wlds[w * E4C + lane + 64];
        float a = 0.f, b = 0.f;
        a = fmaf(xa0.x, w0.x, a); a = fmaf(xa0.y, w0.y, a);
        a = fmaf(xa0.z, w0.z, a); a = fmaf(xa0.w, w0.w, a);
        a = fmaf(xa1.x, w1.x, a); a = fmaf(xa1.y, w1.y, a);
        a = fmaf(xa1.z, w1.z, a); a = fmaf(xa1.w, w1.w, a);
        b = fmaf(xb0.x, w0.x, b); b = fmaf(xb0.y, w0.y, b);
        b = fmaf(xb0.z, w0.z, b); b = fmaf(xb0.w, w0.w, b);
        b = fmaf(xb1.x, w1.x, b); b = fmaf(xb1.y, w1.y, b);
        b = fmaf(xb1.z, w1.z, b); b = fmaf(xb1.w, w1.w, b);
        accA[w] = a; accB[w] = b;
    }

    // full-wave butterfly: every lane ends with the complete e-sum
    #pragma unroll
    for (int w = 0; w < WIN_; ++w) {
        float a = accA[w], b = accB[w];
        a += __shfl_xor(a, 32, 64);  b += __shfl_xor(b, 32, 64);
        a += __shfl_xor(a, 16, 64);  b += __shfl_xor(b, 16, 64);
        a += __shfl_xor(a,  8, 64);  b += __shfl_xor(b,  8, 64);
        a += __shfl_xor(a,  4, 64);  b += __shfl_xor(b,  4, 64);
        a += __shfl_xor(a,  2, 64);  b += __shfl_xor(b,  2, 64);
        a += __shfl_xor(a,  1, 64);  b += __shfl_xor(b,  1, 64);
        accA[w] = a; accB[w] = b;
    }

    // static-index lane select (rule #20: no runtime indexing of acc arrays)
    float va = 0.f, vb = 0.f;
    #pragma unroll
    for (int w = 0; w < WIN_; ++w) {
        if (lane == w)      va = accA[w];
        if (lane == 32 + w) vb = accB[w];
    }
    if (lane < WIN_)
        Pblk[wid * WIN_ + lane] = va;                  // b = wid
    else if (lane >= 32 && lane < 32 + WIN_)
        Pblk[(wid + 4) * WIN_ + (lane - 32)] = vb;     // b = wid+4
}

// ---------------------------------------------------------------------------
// Kernel B: combine partials -> sigmoid gates -> score + tanh (fast exp).
// Block per s (XCD-swizzled), 256 threads. x rows are L2/L3-hot.
// ---------------------------------------------------------------------------
__device__ __forceinline__ float tanh_fast(float v) {
    const float e = __expf(v + v);     // v_exp-based; saturates correctly
    return 1.f - 2.f / (e + 1.f);
}

__global__ __launch_bounds__(256)
void win_score(const float* __restrict__ x,
               const float* __restrict__ bias,
               const float* __restrict__ P,
               float* __restrict__ out)
{
    const int bid = blockIdx.x;
    const int s   = (bid & 7) * (S_ / 8) + (bid >> 3);  // XCD swizzle (2048%8==0)
    const int tid = threadIdx.x;

    __shared__ float Pl[WIN_ * PSTR];   // 968 floats: [wp][b*11+w]
    __shared__ float gates[PSTR];

    const float4* Ps = reinterpret_cast<const float4*>(P + (size_t)s * (WIN_ * PSTR));
    if (tid < (WIN_ * PSTR) / 4)        // 242 coalesced float4 loads
        reinterpret_cast<float4*>(Pl)[tid] = Ps[tid];
    __syncthreads();

    if (tid < PSTR) {
        const int w = tid % WIN_;
        float v = bias[s * WIN_ + w];
        #pragma unroll
        for (int wp = 0; wp < WIN_; ++wp) v += Pl[wp * PSTR + tid];
        gates[tid] = 1.f / (1.f + __expf(-v));
    }
    __syncthreads();

    const float4* __restrict__ X4   = reinterpret_cast<const float4*>(x);
    float4* __restrict__       OUT4 = reinterpret_cast<float4*>(out);

    #pragma unroll
    for (int it = 0; it < 4; ++it) {
        const int i  = tid + (it << 8);   // 0..1023 -> (b, e4)
        const int b  = i >> 7;
        const int e4 = i & 127;
        float4 sc = make_float4(0.f, 0.f, 0.f, 0.f);
        #pragma unroll
        for (int w = 0; w < WIN_; ++w) {
            const int row = s - WW + w;
            if (row >= 0 && row < S_) {
                const float g   = gates[b * WIN_ + w];
                const float4 xv = X4[((size_t)b * S_ + row) * E4C + e4];
                sc.x = fmaf(g, xv.x, sc.x);
                sc.y = fmaf(g, xv.y, sc.y);
                sc.z = fmaf(g, xv.z, sc.z);
                sc.w = fmaf(g, xv.w, sc.w);
            }
        }
        float4 o;
        o.x = tanh_fast(sc.x);
        o.y = tanh_fast(sc.y);
        o.z = tanh_fast(sc.z);
        o.w = tanh_fast(sc.w);
        OUT4[((size_t)b * S_ + s) * E4C + e4] = o;
    }
}

extern "C" void kernel_launch(void* const* d_in, const int* in_sizes, int n_in,
                              void* d_out, int out_size, void* d_ws, size_t ws_size,
                              hipStream_t stream)
{
    const float* x    = (const float*)d_in[0];
    const float* W    = (const float*)d_in[1];
    const float* bias = (const float*)d_in[2];
    float* out        = (float*)d_out;
    float* P          = (float*)d_ws;   // 22528 * 88 floats = 7.93 MB

    win_gate_partial<<<dim3(NBLKA), dim3(256), 0, stream>>>(x, W, P);
    win_score<<<dim3(S_), dim3(256), 0, stream>>>(x, bias, P, out);
}

// Round 6
// 158.459 us; speedup vs baseline: 6.7781x; 1.1455x over previous
//
#include <hip/hip_runtime.h>
#include <math.h>

// Problem constants (B, S, E, WIN) = (8, 2048, 512, 11)
#define B_    8
#define S_    2048
#define E_    512
#define WIN_  11
#define WW    5              // WIN/2
#define F4C   1408           // float4 per W row (5632/4)
#define E4C   128            // float4 per x row (512/4)
#define NBLKA (S_ * WIN_)    // 22528 blocks in kernel A
#define CPX_A (NBLKA / 8)    // 2816 blocks per XCD (exact)
#define PSTR  (B_ * WIN_)    // 88 partials per (s,wp) block

// ---- DPP wave-sum: 6 VALU ops, no DS pipe. Sum of all 64 lanes -> lane 63.
template <int CTRL, int RMASK>
__device__ __forceinline__ float dpp_add(float v) {
    int sh = __builtin_amdgcn_update_dpp(0, __float_as_int(v),
                                         CTRL, RMASK, 0xF, true);
    return v + __int_as_float(sh);
}
__device__ __forceinline__ float wave_sum63(float v) {
    v = dpp_add<0x111, 0xF>(v);   // row_shr:1
    v = dpp_add<0x112, 0xF>(v);   // row_shr:2
    v = dpp_add<0x114, 0xF>(v);   // row_shr:4
    v = dpp_add<0x118, 0xF>(v);   // row_shr:8  -> lane 15 of each 16-row has row sum
    v = dpp_add<0x142, 0xA>(v);   // row_bcast:15 -> lanes 31,63 have 32-group sums
    v = dpp_add<0x143, 0xC>(v);   // row_bcast:31 -> lane 63 has full wave sum
    return v;
}

// ---------------------------------------------------------------------------
// Kernel A: partial gate dot-products.
// Block sw = s*11+wp: stages W[s, :, wp*512:(wp+1)*512] (22.5 KB) into LDS
// via global_load_lds width-16 (W read exactly once from HBM chip-wide).
// Wave g owns window rows 3g..min(3g+2,10) for ALL 8 batches -> each W word
// is ds_read exactly once (1x LDS amplification, was 4x). Reduction is pure
// DPP-VALU (was 528 ds_swizzle per block -> the cross-round plateau).
// ---------------------------------------------------------------------------
__global__ __launch_bounds__(256)
void win_gate_partial(const float* __restrict__ x,
                      const float* __restrict__ W,
                      float* __restrict__ P)
{
    const int bid = blockIdx.x;
    const int sw  = (bid & 7) * CPX_A + (bid >> 3);   // bijective XCD swizzle
    const int s   = sw / WIN_;
    const int wp  = sw - s * WIN_;

    const int tid  = threadIdx.x;
    const int wid  = tid >> 6;      // wave 0..3
    const int lane = tid & 63;

    float* __restrict__ Pblk = P + (size_t)sw * PSTR;

    const int row = s - WW + wp;
    if (row < 0 || row >= S_) {     // block-uniform early out: zero partials
        if (tid < PSTR) Pblk[tid] = 0.f;
        return;
    }

    const float4* __restrict__ X4 = reinterpret_cast<const float4*>(x);
    const float4* __restrict__ W4 = reinterpret_cast<const float4*>(W)
        + (size_t)s * (WIN_ * F4C) + (size_t)wp * E4C;

    __shared__ float4 Wlds[WIN_ * E4C];   // 1408 float4 = 22.5 KB

    // stage the 11 x 128-float4 W pieces (global stride F4C) into linear LDS
    #pragma unroll
    for (int j = 0; j < 6; ++j) {
        const int m = j * 256 + tid;          // float4 index in [0,1536)
        if (j < 5 || wid < 2) {               // wave-uniform guard (m < 1408)
            const int w  = m >> 7;
            const int e4 = m & 127;
            const float4* src = W4 + (size_t)w * F4C + e4;
            __builtin_amdgcn_global_load_lds(
                (const __attribute__((address_space(1))) void*)src,
                (__attribute__((address_space(3))) void*)&Wlds[m],
                16, 0, 0);
        }
    }
    __syncthreads();   // staging complete

    const int w0   = wid * 3;                 // first w-row of this wave
    const int wcnt = (wid == 3) ? 2 : 3;

    // this wave's W fragments: read each LDS word exactly once
    float4 wv[3][2];
    #pragma unroll
    for (int j = 0; j < 3; ++j)
        if (j < wcnt) {
            wv[j][0] = Wlds[(w0 + j) * E4C + lane];
            wv[j][1] = Wlds[(w0 + j) * E4C + lane + 64];
        }

    float acc[B_][3];
    #pragma unroll
    for (int b = 0; b < B_; ++b)
        #pragma unroll
        for (int j = 0; j < 3; ++j) acc[b][j] = 0.f;

    // two 4-batch chunks to bound live x registers (peak ~32 VGPR for x)
    #pragma unroll
    for (int half = 0; half < 2; ++half) {
        float4 xv[4][2];
        #pragma unroll
        for (int bb = 0; bb < 4; ++bb) {
            const int b = half * 4 + bb;
            xv[bb][0] = X4[((size_t)b * S_ + row) * E4C + lane];
            xv[bb][1] = X4[((size_t)b * S_ + row) * E4C + lane + 64];
        }
        #pragma unroll
        for (int bb = 0; bb < 4; ++bb) {
            const int b = half * 4 + bb;
            #pragma unroll
            for (int j = 0; j < 3; ++j) {
                if (j < wcnt) {
                    float a = acc[b][j];
                    a = fmaf(xv[bb][0].x, wv[j][0].x, a);
                    a = fmaf(xv[bb][0].y, wv[j][0].y, a);
                    a = fmaf(xv[bb][0].z, wv[j][0].z, a);
                    a = fmaf(xv[bb][0].w, wv[j][0].w, a);
                    a = fmaf(xv[bb][1].x, wv[j][1].x, a);
                    a = fmaf(xv[bb][1].y, wv[j][1].y, a);
                    a = fmaf(xv[bb][1].z, wv[j][1].z, a);
                    a = fmaf(xv[bb][1].w, wv[j][1].w, a);
                    acc[b][j] = a;
                }
            }
        }
    }

    // DPP reduce (VALU only) -> lane 63 stores its wave's 8b x wcnt partials
    #pragma unroll
    for (int b = 0; b < B_; ++b)
        #pragma unroll
        for (int j = 0; j < 3; ++j)
            if (j < wcnt) acc[b][j] = wave_sum63(acc[b][j]);

    if (lane == 63) {
        #pragma unroll
        for (int b = 0; b < B_; ++b)
            #pragma unroll
            for (int j = 0; j < 3; ++j)
                if (j < wcnt) Pblk[b * WIN_ + w0 + j] = acc[b][j];
    }
}

// ---------------------------------------------------------------------------
// Kernel B: combine partials -> sigmoid gates -> score + tanh (fast exp).
// Block per s (XCD-swizzled), 256 threads. x rows are L2/L3-hot.
// ---------------------------------------------------------------------------
__device__ __forceinline__ float tanh_fast(float v) {
    const float e = __expf(v + v);
    return 1.f - 2.f / (e + 1.f);
}

__global__ __launch_bounds__(256)
void win_score(const float* __restrict__ x,
               const float* __restrict__ bias,
               const float* __restrict__ P,
               float* __restrict__ out)
{
    const int bid = blockIdx.x;
    const int s   = (bid & 7) * (S_ / 8) + (bid >> 3);  // XCD swizzle
    const int tid = threadIdx.x;

    __shared__ float Pl[WIN_ * PSTR];   // 968 floats: [wp][b*11+w]
    __shared__ float gates[PSTR];

    const float4* Ps = reinterpret_cast<const float4*>(P + (size_t)s * (WIN_ * PSTR));
    if (tid < (WIN_ * PSTR) / 4)        // 242 coalesced float4 loads
        reinterpret_cast<float4*>(Pl)[tid] = Ps[tid];
    __syncthreads();

    if (tid < PSTR) {
        const int w = tid % WIN_;
        float v = bias[s * WIN_ + w];
        #pragma unroll
        for (int wp = 0; wp < WIN_; ++wp) v += Pl[wp * PSTR + tid];
        gates[tid] = 1.f / (1.f + __expf(-v));
    }
    __syncthreads();

    const float4* __restrict__ X4   = reinterpret_cast<const float4*>(x);
    float4* __restrict__       OUT4 = reinterpret_cast<float4*>(out);

    #pragma unroll
    for (int it = 0; it < 4; ++it) {
        const int i  = tid + (it << 8);   // 0..1023 -> (b, e4)
        const int b  = i >> 7;
        const int e4 = i & 127;
        float4 sc = make_float4(0.f, 0.f, 0.f, 0.f);
        #pragma unroll
        for (int w = 0; w < WIN_; ++w) {
            const int r = s - WW + w;
            if (r >= 0 && r < S_) {
                const float g   = gates[b * WIN_ + w];
                const float4 xv = X4[((size_t)b * S_ + r) * E4C + e4];
                sc.x = fmaf(g, xv.x, sc.x);
                sc.y = fmaf(g, xv.y, sc.y);
                sc.z = fmaf(g, xv.z, sc.z);
                sc.w = fmaf(g, xv.w, sc.w);
            }
        }
        float4 o;
        o.x = tanh_fast(sc.x);
        o.y = tanh_fast(sc.y);
        o.z = tanh_fast(sc.z);
        o.w = tanh_fast(sc.w);
        OUT4[((size_t)b * S_ + s) * E4C + e4] = o;
    }
}

extern "C" void kernel_launch(void* const* d_in, const int* in_sizes, int n_in,
                              void* d_out, int out_size, void* d_ws, size_t ws_size,
                              hipStream_t stream)
{
    const float* x    = (const float*)d_in[0];
    const float* W    = (const float*)d_in[1];
    const float* bias = (const float*)d_in[2];
    float* out        = (float*)d_out;
    float* P          = (float*)d_ws;   // 22528 * 88 floats = 7.93 MB

    win_gate_partial<<<dim3(NBLKA), dim3(256), 0, stream>>>(x, W, P);
    win_score<<<dim3(S_), dim3(256), 0, stream>>>(x, bias, P, out);
}

// Round 7
// 155.997 us; speedup vs baseline: 6.8851x; 1.0158x over previous
//
#include <hip/hip_runtime.h>
#include <math.h>

// Problem constants (B, S, E, WIN) = (8, 2048, 512, 11)
#define B_    8
#define S_    2048
#define E_    512
#define WIN_  11
#define WW    5              // WIN/2
#define F4C   1408           // float4 per W row (5632/4)
#define E4C   128            // float4 per x row (512/4)
#define PSTR  (B_ * WIN_)    // 88 gate logits per s

// ---- DPP wave-sum: 6 VALU ops, zero DS-pipe traffic. Full sum -> lane 63.
template <int CTRL, int RMASK>
__device__ __forceinline__ float dpp_add(float v) {
    int sh = __builtin_amdgcn_update_dpp(0, __float_as_int(v),
                                         CTRL, RMASK, 0xF, true);
    return v + __int_as_float(sh);
}
__device__ __forceinline__ float wave_sum63(float v) {
    v = dpp_add<0x111, 0xF>(v);   // row_shr:1
    v = dpp_add<0x112, 0xF>(v);   // row_shr:2
    v = dpp_add<0x114, 0xF>(v);   // row_shr:4
    v = dpp_add<0x118, 0xF>(v);   // row_shr:8
    v = dpp_add<0x142, 0xA>(v);   // row_bcast:15
    v = dpp_add<0x143, 0xC>(v);   // row_bcast:31 -> lane 63 = full sum
    return v;
}

__device__ __forceinline__ float tanh_fast(float v) {
    const float e = __expf(v + v);
    return 1.f - 2.f / (e + 1.f);
}

// ---------------------------------------------------------------------------
// Fully fused: block per s (2048 blocks, XCD-swizzled), 256 threads = 4 waves.
// Loop over the 11 wp-chunks of W[s] (22.5 KB each):
//   stage chunk via global_load_lds(16B) -> barrier -> FMA into acc[8][3]
//   (wave g owns w-rows 3g..3g+2; lanes cover e4 {lane, lane+64}) -> barrier.
// Cross-block overlap (~5 blocks/CU) keeps the W HBM stream saturated while
// individual blocks sit in their barrier drains.
// Epilogue: DPP reduce -> gates in LDS -> sigmoid -> score + tanh_fast.
// W read exactly once chip-wide; x L2/L3-hot; no partial round-trip, no 2nd
// kernel, no 2nd x fetch.
// ---------------------------------------------------------------------------
__global__ __launch_bounds__(256)
void win_attn_fused(const float* __restrict__ x,
                    const float* __restrict__ W,
                    const float* __restrict__ bias,
                    float* __restrict__ out)
{
    const int bid  = blockIdx.x;
    const int s    = (bid & 7) * (S_ / 8) + (bid >> 3);   // bijective XCD swizzle
    const int tid  = threadIdx.x;
    const int wid  = tid >> 6;      // wave 0..3
    const int lane = tid & 63;

    const float4* __restrict__ X4 = reinterpret_cast<const float4*>(x);
    const float4* __restrict__ Ws = reinterpret_cast<const float4*>(W)
                                    + (size_t)s * (WIN_ * F4C);

    __shared__ float4 Wbuf[WIN_ * E4C];   // 22.5 KB: [w][e4] for current wp
    __shared__ float gates[PSTR];

    const int w0   = wid * 3;                  // first w-row of this wave
    const int wcnt = (wid == 3) ? 2 : 3;       // wave 3 owns rows 9,10

    float acc[B_][3];
    #pragma unroll
    for (int b = 0; b < B_; ++b)
        #pragma unroll
        for (int j = 0; j < 3; ++j) acc[b][j] = 0.f;

    #pragma unroll 1
    for (int wp = 0; wp < WIN_; ++wp) {
        // ---- stage W[s, :, wp*512:(wp+1)*512] into LDS (1408 float4) ----
        #pragma unroll
        for (int j = 0; j < 6; ++j) {
            const int m = j * 256 + tid;          // float4 index in [0,1536)
            if (j < 5 || wid < 2) {               // wave-uniform guard (m<1408)
                const int w  = m >> 7;
                const int e4 = m & 127;
                const float4* src = Ws + (size_t)w * F4C + wp * E4C + e4;
                __builtin_amdgcn_global_load_lds(
                    (const __attribute__((address_space(1))) void*)src,
                    (__attribute__((address_space(3))) void*)&Wbuf[m],
                    16, 0, 0);
            }
        }
        __syncthreads();   // staging complete

        const int row = s - WW + wp;
        if (row >= 0 && row < S_) {              // block-uniform (PAD contributes 0)
            float4 wv[3][2];
            #pragma unroll
            for (int j = 0; j < 3; ++j)
                if (j < wcnt) {
                    wv[j][0] = Wbuf[(w0 + j) * E4C + lane];
                    wv[j][1] = Wbuf[(w0 + j) * E4C + lane + 64];
                }

            // two 4-batch chunks to bound live x registers
            #pragma unroll
            for (int half = 0; half < 2; ++half) {
                float4 xv[4][2];
                #pragma unroll
                for (int bb = 0; bb < 4; ++bb) {
                    const int b = half * 4 + bb;
                    xv[bb][0] = X4[((size_t)b * S_ + row) * E4C + lane];
                    xv[bb][1] = X4[((size_t)b * S_ + row) * E4C + lane + 64];
                }
                #pragma unroll
                for (int bb = 0; bb < 4; ++bb) {
                    const int b = half * 4 + bb;
                    #pragma unroll
                    for (int j = 0; j < 3; ++j) {
                        if (j < wcnt) {
                            float a = acc[b][j];
                            a = fmaf(xv[bb][0].x, wv[j][0].x, a);
                            a = fmaf(xv[bb][0].y, wv[j][0].y, a);
                            a = fmaf(xv[bb][0].z, wv[j][0].z, a);
                            a = fmaf(xv[bb][0].w, wv[j][0].w, a);
                            a = fmaf(xv[bb][1].x, wv[j][1].x, a);
                            a = fmaf(xv[bb][1].y, wv[j][1].y, a);
                            a = fmaf(xv[bb][1].z, wv[j][1].z, a);
                            a = fmaf(xv[bb][1].w, wv[j][1].w, a);
                            acc[b][j] = a;
                        }
                    }
                }
            }
        }
        __syncthreads();   // WAR: all waves done reading Wbuf before next stage
    }

    // ---- DPP reduce -> gate logits -> sigmoid ----
    #pragma unroll
    for (int b = 0; b < B_; ++b)
        #pragma unroll
        for (int j = 0; j < 3; ++j)
            if (j < wcnt) acc[b][j] = wave_sum63(acc[b][j]);

    if (lane == 63) {
        #pragma unroll
        for (int b = 0; b < B_; ++b)
            #pragma unroll
            for (int j = 0; j < 3; ++j)
                if (j < wcnt) gates[b * WIN_ + w0 + j] = acc[b][j];
    }
    __syncthreads();

    if (tid < PSTR) {
        const int w = tid % WIN_;
        const float v = gates[tid] + bias[s * WIN_ + w];
        gates[tid] = 1.f / (1.f + __expf(-v));
    }
    __syncthreads();

    // ---- score + tanh (x rows L1/L2-hot from the chunk loop) ----
    float4* __restrict__ OUT4 = reinterpret_cast<float4*>(out);
    #pragma unroll
    for (int it = 0; it < 4; ++it) {
        const int i  = tid + (it << 8);   // 0..1023 -> (b, e4)
        const int b  = i >> 7;
        const int e4 = i & 127;
        float4 sc = make_float4(0.f, 0.f, 0.f, 0.f);
        #pragma unroll
        for (int w = 0; w < WIN_; ++w) {
            const int r = s - WW + w;
            if (r >= 0 && r < S_) {
                const float g   = gates[b * WIN_ + w];
                const float4 xv = X4[((size_t)b * S_ + r) * E4C + e4];
                sc.x = fmaf(g, xv.x, sc.x);
                sc.y = fmaf(g, xv.y, sc.y);
                sc.z = fmaf(g, xv.z, sc.z);
                sc.w = fmaf(g, xv.w, sc.w);
            }
        }
        float4 o;
        o.x = tanh_fast(sc.x);
        o.y = tanh_fast(sc.y);
        o.z = tanh_fast(sc.z);
        o.w = tanh_fast(sc.w);
        OUT4[((size_t)b * S_ + s) * E4C + e4] = o;
    }
}

extern "C" void kernel_launch(void* const* d_in, const int* in_sizes, int n_in,
                              void* d_out, int out_size, void* d_ws, size_t ws_size,
                              hipStream_t stream)
{
    const float* x    = (const float*)d_in[0];
    const float* W    = (const float*)d_in[1];
    const float* bias = (const float*)d_in[2];
    float* out        = (float*)d_out;

    win_attn_fused<<<dim3(S_), dim3(256), 0, stream>>>(x, W, bias, out);
}

// Round 8
// 155.789 us; speedup vs baseline: 6.8943x; 1.0013x over previous
//
#include <hip/hip_runtime.h>
#include <math.h>

// Problem constants (B, S, E, WIN) = (8, 2048, 512, 11)
#define B_    8
#define S_    2048
#define E_    512
#define WIN_  11
#define WW    5              // WIN/2
#define F4C   1408           // float4 per W row (5632/4)
#define E4C   128            // float4 per x row (512/4)
#define PSTR  (B_ * WIN_)    // 88 gate logits per s

// ---- DPP wave-sum: 6 VALU ops, zero DS-pipe traffic. Full sum -> lane 63.
template <int CTRL, int RMASK>
__device__ __forceinline__ float dpp_add(float v) {
    int sh = __builtin_amdgcn_update_dpp(0, __float_as_int(v),
                                         CTRL, RMASK, 0xF, true);
    return v + __int_as_float(sh);
}
__device__ __forceinline__ float wave_sum63(float v) {
    v = dpp_add<0x111, 0xF>(v);   // row_shr:1
    v = dpp_add<0x112, 0xF>(v);   // row_shr:2
    v = dpp_add<0x114, 0xF>(v);   // row_shr:4
    v = dpp_add<0x118, 0xF>(v);   // row_shr:8
    v = dpp_add<0x142, 0xA>(v);   // row_bcast:15
    v = dpp_add<0x143, 0xC>(v);   // row_bcast:31 -> lane 63 = full sum
    return v;
}

__device__ __forceinline__ float tanh_fast(float v) {
    const float e = __expf(v + v);
    return 1.f - 2.f / (e + 1.f);
}

// ---------------------------------------------------------------------------
// Fused, 2-phase double-buffered (T3-minimum schedule):
//   prologue: STAGE(buf0, wp=0); barrier
//   iter wp : STAGE(buf[cur^1], wp+1)   <- loads fly during compute
//             compute chunk wp from buf[cur] (ds_read + FMA, x loads hot)
//             barrier (vmcnt(0) drains next-chunk loads AFTER compute)
// WAR-safe with ONE barrier/iter: reads of buf[cur] are lgkmcnt-complete
// before the end-of-iter barrier; buf[cur] is only overwritten after it.
// Block per s (2048, XCD-swizzled), 256 thr = 4 waves; wave g owns w-rows
// 3g..3g+2 for all 8 batches; lanes cover e4 {lane, lane+64}.
// W read exactly once chip-wide via global_load_lds(16B); invalid (padded)
// rows skip both staging and compute.
// ---------------------------------------------------------------------------
__global__ __launch_bounds__(256)
void win_attn_fused(const float* __restrict__ x,
                    const float* __restrict__ W,
                    const float* __restrict__ bias,
                    float* __restrict__ out)
{
    const int bid  = blockIdx.x;
    const int s    = (bid & 7) * (S_ / 8) + (bid >> 3);   // bijective XCD swizzle
    const int tid  = threadIdx.x;
    const int wid  = tid >> 6;      // wave 0..3
    const int lane = tid & 63;

    const float4* __restrict__ X4 = reinterpret_cast<const float4*>(x);
    const float4* __restrict__ Ws = reinterpret_cast<const float4*>(W)
                                    + (size_t)s * (WIN_ * F4C);

    __shared__ float4 Wbuf[2][WIN_ * E4C];   // 2 x 22.5 KB double buffer
    __shared__ float gates[PSTR];

    const int w0   = wid * 3;                  // first w-row of this wave
    const int wcnt = (wid == 3) ? 2 : 3;       // wave 3 owns rows 9,10

    // stage chunk wp into Wbuf[buf]: 1408 float4, 16B global_load_lds
    auto STAGE = [&](int buf, int wp) {
        #pragma unroll
        for (int j = 0; j < 6; ++j) {
            const int m = j * 256 + tid;          // float4 index in [0,1536)
            if (j < 5 || wid < 2) {               // wave-uniform guard (m<1408)
                const int w  = m >> 7;
                const int e4 = m & 127;
                const float4* src = Ws + (size_t)w * F4C + wp * E4C + e4;
                __builtin_amdgcn_global_load_lds(
                    (const __attribute__((address_space(1))) void*)src,
                    (__attribute__((address_space(3))) void*)&Wbuf[buf][m],
                    16, 0, 0);
            }
        }
    };

    float acc[B_][3];
    #pragma unroll
    for (int b = 0; b < B_; ++b)
        #pragma unroll
        for (int j = 0; j < 3; ++j) acc[b][j] = 0.f;

    // prologue: first valid chunk is wp = WW - min(s,WW) ... but padded rows
    // contribute zero; for s>=5 wp=0 is valid. Stage wp=0 only if valid.
    if (s - WW >= 0) STAGE(0, 0);
    __syncthreads();

    int cur = 0;
    #pragma unroll 1
    for (int wp = 0; wp < WIN_; ++wp) {
        // issue next chunk's staging before computing current (2-phase overlap)
        if (wp + 1 < WIN_) {
            const int nrow = s - WW + (wp + 1);
            if (nrow >= 0 && nrow < S_) STAGE(cur ^ 1, wp + 1);
        }

        const int row = s - WW + wp;
        if (row >= 0 && row < S_) {              // block-uniform
            // x loads first (independent of LDS) to hide their latency
            float4 xv[B_][2];
            #pragma unroll
            for (int b = 0; b < B_; ++b) {
                xv[b][0] = X4[((size_t)b * S_ + row) * E4C + lane];
                xv[b][1] = X4[((size_t)b * S_ + row) * E4C + lane + 64];
            }

            float4 wv[3][2];
            #pragma unroll
            for (int j = 0; j < 3; ++j)
                if (j < wcnt) {
                    wv[j][0] = Wbuf[cur][(w0 + j) * E4C + lane];
                    wv[j][1] = Wbuf[cur][(w0 + j) * E4C + lane + 64];
                }

            #pragma unroll
            for (int b = 0; b < B_; ++b)
                #pragma unroll
                for (int j = 0; j < 3; ++j)
                    if (j < wcnt) {
                        float a = acc[b][j];
                        a = fmaf(xv[b][0].x, wv[j][0].x, a);
                        a = fmaf(xv[b][0].y, wv[j][0].y, a);
                        a = fmaf(xv[b][0].z, wv[j][0].z, a);
                        a = fmaf(xv[b][0].w, wv[j][0].w, a);
                        a = fmaf(xv[b][1].x, wv[j][1].x, a);
                        a = fmaf(xv[b][1].y, wv[j][1].y, a);
                        a = fmaf(xv[b][1].z, wv[j][1].z, a);
                        a = fmaf(xv[b][1].w, wv[j][1].w, a);
                        acc[b][j] = a;
                    }
        }
        __syncthreads();   // drains vmcnt(0): next chunk staged; WAR-safe
        cur ^= 1;
    }

    // ---- DPP reduce -> gate logits -> sigmoid ----
    #pragma unroll
    for (int b = 0; b < B_; ++b)
        #pragma unroll
        for (int j = 0; j < 3; ++j)
            if (j < wcnt) acc[b][j] = wave_sum63(acc[b][j]);

    if (lane == 63) {
        #pragma unroll
        for (int b = 0; b < B_; ++b)
            #pragma unroll
            for (int j = 0; j < 3; ++j)
                if (j < wcnt) gates[b * WIN_ + w0 + j] = acc[b][j];
    }
    __syncthreads();

    if (tid < PSTR) {
        const int w = tid % WIN_;
        const float v = gates[tid] + bias[s * WIN_ + w];
        gates[tid] = 1.f / (1.f + __expf(-v));
    }
    __syncthreads();

    // ---- score + tanh (x rows L1/L2-hot from the chunk loop) ----
    float4* __restrict__ OUT4 = reinterpret_cast<float4*>(out);
    #pragma unroll
    for (int it = 0; it < 4; ++it) {
        const int i  = tid + (it << 8);   // 0..1023 -> (b, e4)
        const int b  = i >> 7;
        const int e4 = i & 127;
        float4 sc = make_float4(0.f, 0.f, 0.f, 0.f);
        #pragma unroll
        for (int w = 0; w < WIN_; ++w) {
            const int r = s - WW + w;
            if (r >= 0 && r < S_) {
                const float g   = gates[b * WIN_ + w];
                const float4 xv = X4[((size_t)b * S_ + r) * E4C + e4];
                sc.x = fmaf(g, xv.x, sc.x);
                sc.y = fmaf(g, xv.y, sc.y);
                sc.z = fmaf(g, xv.z, sc.z);
                sc.w = fmaf(g, xv.w, sc.w);
            }
        }
        float4 o;
        o.x = tanh_fast(sc.x);
        o.y = tanh_fast(sc.y);
        o.z = tanh_fast(sc.z);
        o.w = tanh_fast(sc.w);
        OUT4[((size_t)b * S_ + s) * E4C + e4] = o;
    }
}

extern "C" void kernel_launch(void* const* d_in, const int* in_sizes, int n_in,
                              void* d_out, int out_size, void* d_ws, size_t ws_size,
                              hipStream_t stream)
{
    const float* x    = (const float*)d_in[0];
    const float* W    = (const float*)d_in[1];
    const float* bias = (const float*)d_in[2];
    float* out        = (float*)d_out;

    win_attn_fused<<<dim3(S_), dim3(256), 0, stream>>>(x, W, bias, out);
}